// Round 20
// baseline (144.141 us; speedup 1.0000x reference)
//
#include <hip/hip_runtime.h>

typedef __bf16 bf16;
typedef __attribute__((ext_vector_type(8))) __bf16 bf16x8;
typedef __attribute__((ext_vector_type(2))) __bf16 bf16x2;
typedef __attribute__((ext_vector_type(4))) float f32x4;

#define AS1 __attribute__((address_space(1)))
#define AS3 __attribute__((address_space(3)))

// Problem constants
#define BB 2
#define SS 2048
#define DD 1024
#define HH 16
#define HD 64
#define BH (BB*HH)

// 0.125 (1/sqrt(64)) * 1/ln(2): folded into Q so scores come out in log2 units
#define QSCALE 0.1803368801111244f

static __device__ __forceinline__ f32x4 mfma16(bf16x8 a, bf16x8 b, f32x4 c) {
  return __builtin_amdgcn_mfma_f32_16x16x32_bf16(a, b, c, 0, 0, 0);
}
static __device__ __forceinline__ float fexp2(float x) {
  return __builtin_amdgcn_exp2f(x);
}

// XCD-aware remap, 1024-block grids: all 32 blocks of a bh on one XCD.
static __device__ __forceinline__ void swz1024(int bid, int& bh, int& a, int& b2) {
  int c = bid & 7, j = bid >> 3;
  bh = c + 8 * (j & 3);
  int rem = j >> 2;          // 0..31
  a = rem & 15;
  b2 = rem >> 4;
}

// ---------------- fp32 -> bf16 conversion (weights only; inputs fused into proj) --------
__global__ __launch_bounds__(256) void cvt_w(const float* __restrict__ s0, const float* __restrict__ s1,
                                             const float* __restrict__ s2, const float* __restrict__ s3,
                                             bf16* __restrict__ o0, bf16* __restrict__ o1,
                                             bf16* __restrict__ o2, bf16* __restrict__ o3) {
  const int z = blockIdx.y;
  const float* s = (z == 0) ? s0 : (z == 1) ? s1 : (z == 2) ? s2 : s3;
  bf16* o = (z == 0) ? o0 : (z == 1) ? o1 : (z == 2) ? o2 : o3;
  int i = blockIdx.x * 256 + threadIdx.x;
  const float4* sp = (const float4*)s;
  float4 a = sp[2 * i], b = sp[2 * i + 1];
  bf16x8 v;
  v[0] = (bf16)a.x; v[1] = (bf16)a.y; v[2] = (bf16)a.z; v[3] = (bf16)a.w;
  v[4] = (bf16)b.x; v[5] = (bf16)b.y; v[6] = (bf16)b.z; v[7] = (bf16)b.w;
  ((bf16x8*)o)[i] = v;
}

// ---------------- batched QKV projection, cvt_x FUSED via reg->bf16->ds_write -----------
// 1D grid 768, XCD decode: XCD c owns m-tiles [4c,4c+4) across all n,z.
// A: fp32 loaded to REGS during previous step's compute (T14 split: issue after barrier1,
// latency hides under MFMA), converted to bf16, ds_write'd into the R15 bf16 LDS layout
// (slot c^((r>>1)&3); write = 2-way/phase = free; reads bit-identical to R15's 0-conflict
// pattern). B: bf16 via global_load_lds (R15). Numerics identical to separate cvt_x.
// z=0: Q (prescaled) -> [BH][S][64]; z=1: K -> [BH][S][64]; z=2: V tile-major.
__global__ __launch_bounds__(256) void proj_gemm(
    const float* __restrict__ Xq, const float* __restrict__ Xk, const float* __restrict__ Xv,
    const bf16* __restrict__ Wq, const bf16* __restrict__ Wk, const bf16* __restrict__ Wv,
    const float* __restrict__ bq, const float* __restrict__ bk, const float* __restrict__ bv,
    bf16* __restrict__ Oq, bf16* __restrict__ Ok, bf16* __restrict__ Ovt) {
  __shared__ __align__(16) bf16 sA[128 * 32];
  __shared__ __align__(16) bf16 sB[128 * 32];
  const int bid = blockIdx.x;
  const int c = bid & 7, u = bid >> 3;
  const int mt = c * 4 + (u & 3);   // 0..31
  const int nt = (u >> 2) & 7;     // 0..7
  const int z = u >> 5;            // 0..2
  const float* X = (z == 0) ? Xq : ((z == 1) ? Xk : Xv);
  const bf16* W = (z == 0) ? Wq : ((z == 1) ? Wk : Wv);
  const float* bias = (z == 0) ? bq : ((z == 1) ? bk : bv);
  const int tid = threadIdx.x, l = tid & 63, w = tid >> 6;
  const int m0 = mt * 128, n0 = nt * 128;
  const int l15 = l & 15, lg = l >> 4;
  const int wr = (w >> 1) * 64, wc = (w & 1) * 64;
  const int fv = (l15 >> 1) & 3;

  // A reg-staging geometry: thread t owns row ra = t>>1, half ha = t&1
  // (fp32 elements 16*ha .. 16*ha+15 of the row's 32-wide K-chunk)
  const int ra = tid >> 1, ha = tid & 1;
  const float* gA = X + (size_t)(m0 + ra) * DD + ha * 16;
  const int fra = (ra >> 1) & 3;
  bf16* dA0 = sA + ra * 32 + ((2 * ha) ^ fra) * 8;
  bf16* dA1 = sA + ra * 32 + ((2 * ha + 1) ^ fra) * 8;

  float4 ar0 = *(const float4*)(gA + 0);
  float4 ar1 = *(const float4*)(gA + 4);
  float4 ar2 = *(const float4*)(gA + 8);
  float4 ar3 = *(const float4*)(gA + 12);

  f32x4 acc[4][4] = {};
  for (int kt = 0; kt < DD; kt += 32) {
    // write current A regs (converted) into swizzled bf16 LDS
    bf16x8 o0, o1;
    o0[0] = (bf16)ar0.x; o0[1] = (bf16)ar0.y; o0[2] = (bf16)ar0.z; o0[3] = (bf16)ar0.w;
    o0[4] = (bf16)ar1.x; o0[5] = (bf16)ar1.y; o0[6] = (bf16)ar1.z; o0[7] = (bf16)ar1.w;
    o1[0] = (bf16)ar2.x; o1[1] = (bf16)ar2.y; o1[2] = (bf16)ar2.z; o1[3] = (bf16)ar2.w;
    o1[4] = (bf16)ar3.x; o1[5] = (bf16)ar3.y; o1[6] = (bf16)ar3.z; o1[7] = (bf16)ar3.w;
    *(bf16x8*)dA0 = o0;
    *(bf16x8*)dA1 = o1;
    // stage B (async, R15 swizzle)
#pragma unroll
    for (int i = 0; i < 2; ++i) {
      int t = i * 256 + tid;
      int r = t >> 2, cs = (t & 3) ^ ((r >> 1) & 3);
      const bf16* gb = W + (size_t)(n0 + r) * DD + kt + cs * 8;
      __builtin_amdgcn_global_load_lds((const AS1 void*)gb, (AS3 void*)(sB + t * 8), 16, 0, 0);
    }
    __syncthreads();
    // prefetch next step's A regs; latency hides under this step's MFMAs
    if (kt + 32 < DD) {
      const float* g = gA + kt + 32;
      ar0 = *(const float4*)(g + 0);
      ar1 = *(const float4*)(g + 4);
      ar2 = *(const float4*)(g + 8);
      ar3 = *(const float4*)(g + 12);
    }
    bf16x8 af[4], bfr[4];
#pragma unroll
    for (int m = 0; m < 4; ++m)
      af[m] = *(const bf16x8*)(sA + (wr + m * 16 + l15) * 32 + (lg ^ fv) * 8);
#pragma unroll
    for (int n = 0; n < 4; ++n)
      bfr[n] = *(const bf16x8*)(sB + (wc + n * 16 + l15) * 32 + (lg ^ fv) * 8);
#pragma unroll
    for (int m = 0; m < 4; ++m)
#pragma unroll
      for (int n = 0; n < 4; ++n)
        acc[m][n] = mfma16(af[m], bfr[n], acc[m][n]);
    __syncthreads();
  }
#pragma unroll
  for (int n = 0; n < 4; ++n) {
    int col = n0 + wc + n * 16 + l15;
    float bb = bias[col];
    int h = col >> 6, d = col & 63;
#pragma unroll
    for (int m = 0; m < 4; ++m) {
#pragma unroll
      for (int r = 0; r < 4; ++r) {
        int row = m0 + wr + m * 16 + lg * 4 + r;
        int b = row >> 11, s = row & (SS - 1);
        float vv = acc[m][n][r] + bb;
        if (z == 0) vv *= QSCALE;
        if (z != 2)
          ((z == 0) ? Oq : Ok)[(((size_t)(b * HH + h)) * SS + s) * HD + d] = (bf16)vv;
        else
          Ovt[(size_t)(b * HH + h) * SS * HD + ((s >> 5) * 64 + d) * 32 + (s & 31)] = (bf16)vv;
      }
    }
  }
}

// ---------------- core 128x128 bf16 NT GEMM (C = A * B^T), BK=32 (out_gemm) -------------
__device__ __forceinline__ void gemm_core(const bf16* __restrict__ A,
                                          const bf16* __restrict__ Bm, int K,
                                          int m0, int n0, int w, int l,
                                          bf16* sA, bf16* sB, f32x4 (&acc)[4][4]) {
  const int l15 = l & 15, lg = l >> 4;
  const int wr = (w >> 1) * 64, wc = (w & 1) * 64;
  const int fv = (l15 >> 1) & 3;
  for (int kt = 0; kt < K; kt += 32) {
#pragma unroll
    for (int i = 0; i < 2; ++i) {
      int t = i * 256 + w * 64 + l;
      const int r = t >> 2, cs = (t & 3) ^ ((r >> 1) & 3);
      const bf16* ga = A + (size_t)(m0 + r) * K + kt + cs * 8;
      const bf16* gb = Bm + (size_t)(n0 + r) * K + kt + cs * 8;
      __builtin_amdgcn_global_load_lds((const AS1 void*)ga,
                                       (AS3 void*)(sA + (i * 256 + w * 64) * 8), 16, 0, 0);
      __builtin_amdgcn_global_load_lds((const AS1 void*)gb,
                                       (AS3 void*)(sB + (i * 256 + w * 64) * 8), 16, 0, 0);
    }
    __syncthreads();
    bf16x8 af[4], bfr[4];
#pragma unroll
    for (int m = 0; m < 4; ++m)
      af[m] = *(const bf16x8*)(sA + (wr + m * 16 + l15) * 32 + (lg ^ fv) * 8);
#pragma unroll
    for (int n = 0; n < 4; ++n)
      bfr[n] = *(const bf16x8*)(sB + (wc + n * 16 + l15) * 32 + (lg ^ fv) * 8);
#pragma unroll
    for (int m = 0; m < 4; ++m)
#pragma unroll
      for (int n = 0; n < 4; ++n)
        acc[m][n] = mfma16(af[m], bfr[n], acc[m][n]);
    __syncthreads();
  }
}

// ---------------- output projection: out = ctx @ Wo^T + bo (fp32 out) ----------------
__global__ __launch_bounds__(256) void out_gemm(const bf16* __restrict__ A,
                                                const bf16* __restrict__ W,
                                                const float* __restrict__ bias,
                                                float* __restrict__ out) {
  __shared__ __align__(16) bf16 sA[128 * 32];
  __shared__ __align__(16) bf16 sB[128 * 32];
  const int bid = blockIdx.x;
  const int c = bid & 7, u = bid >> 3;
  const int mt = c * 4 + (u & 3);   // 0..31
  const int nt = (u >> 2) & 7;     // 0..7
  const int tid = threadIdx.x, l = tid & 63, w = tid >> 6;
  const int m0 = mt * 128, n0 = nt * 128;
  f32x4 acc[4][4] = {};
  gemm_core(A, W, DD, m0, n0, w, l, sA, sB, acc);
  const int l15 = l & 15, lg = l >> 4;
  const int wr = (w >> 1) * 64, wc = (w & 1) * 64;
#pragma unroll
  for (int n = 0; n < 4; ++n) {
    int col = n0 + wc + n * 16 + l15;
    float bb = bias[col];
#pragma unroll
    for (int m = 0; m < 4; ++m)
#pragma unroll
      for (int r = 0; r < 4; ++r) {
        int row = m0 + wr + m * 16 + lg * 4 + r;
        out[(size_t)row * DD + col] = acc[m][n][r] + bb;
      }
  }
}

// ---------------- pass A: per-column partial softmax denominator -----------------------
__global__ __launch_bounds__(256) void colz(const bf16* __restrict__ Qb,
                                            const bf16* __restrict__ Kb,
                                            float* __restrict__ zPart) {
  __shared__ float zred[4][64];
  int bh, pair, qh;
  swz1024(blockIdx.x, bh, pair, qh);
  const int tid = threadIdx.x, l = tid & 63, w = tid >> 6;
  const int l15 = l & 15, lg = l >> 4;
  const bf16* Q = Qb + (size_t)bh * SS * HD;
  const bf16* Kh = Kb + (size_t)bh * SS * HD;

  for (int half = 0; half < 2; ++half) {
    const int s = half ? (31 - pair) : pair;
    const int c0 = s * 64;
    bf16x8 kf[4][2];
#pragma unroll
    for (int kt = 0; kt < 4; ++kt) {
      kf[kt][0] = *(const bf16x8*)&Kh[(c0 + kt * 16 + l15) * HD + lg * 8];
      kf[kt][1] = *(const bf16x8*)&Kh[(c0 + kt * 16 + l15) * HD + 32 + lg * 8];
    }
    float z[4] = {};
    const int qstart = c0 + qh * 64 + w * 16;
    bf16x8 qa0, qa1, qn0, qn1;
    if (qstart < SS) {
      qa0 = *(const bf16x8*)&Q[(qstart + l15) * HD + lg * 8];
      qa1 = *(const bf16x8*)&Q[(qstart + l15) * HD + 32 + lg * 8];
    }
    for (int qb = qstart; qb < SS; qb += 128) {
      const int qnext = qb + 128;
      if (qnext < SS) {
        qn0 = *(const bf16x8*)&Q[(qnext + l15) * HD + lg * 8];
        qn1 = *(const bf16x8*)&Q[(qnext + l15) * HD + 32 + lg * 8];
      }
      f32x4 d[4] = {};
#pragma unroll
      for (int kt = 0; kt < 4; ++kt) {
        d[kt] = mfma16(qa0, kf[kt][0], d[kt]);
        d[kt] = mfma16(qa1, kf[kt][1], d[kt]);
      }
#pragma unroll
      for (int kt = 0; kt < 4; ++kt) {
        const int kcol = c0 + kt * 16 + l15;
#pragma unroll
        for (int r = 0; r < 4; ++r) {
          int qq = qb + lg * 4 + r;
          z[kt] += (qq > kcol) ? fexp2(d[kt][r]) : 0.f;
        }
      }
      qa0 = qn0; qa1 = qn1;
    }
#pragma unroll
    for (int kt = 0; kt < 4; ++kt) {
      z[kt] += __shfl_xor(z[kt], 16);
      z[kt] += __shfl_xor(z[kt], 32);
    }
    if (l < 16) {
#pragma unroll
      for (int kt = 0; kt < 4; ++kt) zred[w][kt * 16 + l15] = z[kt];
    }
    __syncthreads();
    if (tid < 64) {
      float zs = zred[0][tid] + zred[1][tid] + zred[2][tid] + zred[3][tid];
      zPart[((size_t)qh * BH + bh) * SS + c0 + tid] = zs;
    }
    __syncthreads();
  }
}

// ---------------- prescale tile-major V by rz = 1/(z0+z1) (rzfin fused); save vlast -----
__global__ __launch_bounds__(256) void vscale(bf16* __restrict__ Vt,
                                              const float* __restrict__ zPart,
                                              float* __restrict__ vlastB) {
  int i = blockIdx.x * 256 + threadIdx.x;  // bf16x8 index over BH*64*64*4
  int ks8 = i & 3;
  int d = (i >> 2) & 63;
  int ts = (i >> 8) & 63;
  int bh = i >> 14;
  bf16* p = Vt + ((((size_t)bh * 64 + ts) * 64 + d) * 32) + ks8 * 8;
  const float* z0 = zPart + (size_t)bh * SS + ts * 32 + ks8 * 8;
  const float* z1 = zPart + ((size_t)BH + bh) * SS + ts * 32 + ks8 * 8;
  bf16x8 v = *(const bf16x8*)p;
  if (ts == 63 && ks8 == 3) vlastB[bh * 64 + d] = (float)v[7] * (1.0f / (float)SS);
  f32x4 a0 = *(const f32x4*)z0, a1 = *(const f32x4*)(z0 + 4);
  f32x4 b0 = *(const f32x4*)z1, b1 = *(const f32x4*)(z1 + 4);
  f32x4 r0, r1;
#pragma unroll
  for (int j = 0; j < 4; ++j) {
    float s0 = a0[j] + b0[j], s1 = a1[j] + b1[j];
    r0[j] = (s0 > 0.f) ? 1.0f / s0 : 0.f;
    r1[j] = (s1 > 0.f) ? 1.0f / s1 : 0.f;
  }
  bf16x8 o;
#pragma unroll
  for (int j = 0; j < 4; ++j) o[j] = (bf16)((float)v[j] * r0[j]);
#pragma unroll
  for (int j = 0; j < 4; ++j) o[4 + j] = (bf16)((float)v[4 + j] * r1[j]);
  *(bf16x8*)p = o;
}

// ---------------- pass B: LDS-staged flash loop with XOR-swizzled tiles -----------------
template <bool DIAG>
static __device__ __forceinline__ void chunk_compute(
    const bf16* sKe, const bf16* sVe, int k0, int qw,
    const bf16x8 (&qa)[2][2], f32x4 (&acc)[2][4], int l15, int lg) {
  const int fv = (l15 >> 1) & 3;           // row-swizzle factor (row mod 16 ≡ l15)
  const int slK = (lg ^ fv) * 8;
  bf16x8 kf00 = *(const bf16x8*)(sKe + l15 * 32 + slK);
  bf16x8 kf01 = *(const bf16x8*)(sKe + 1024 + l15 * 32 + slK);
  bf16x8 kf10 = *(const bf16x8*)(sKe + (16 + l15) * 32 + slK);
  bf16x8 kf11 = *(const bf16x8*)(sKe + 1024 + (16 + l15) * 32 + slK);
  union U { unsigned int u[4]; bf16x8 v; };
  U vf[4];
#pragma unroll
  for (int dt = 0; dt < 4; ++dt) {
    const bf16* base = sVe + (dt * 16 + l15) * 32;
    uint2 lo = *(const uint2*)&base[((lg >> 1) ^ fv) * 8 + (lg & 1) * 4];
    uint2 hi = *(const uint2*)&base[(((lg >> 1) + 2) ^ fv) * 8 + (lg & 1) * 4];
    vf[dt].u[0] = lo.x; vf[dt].u[1] = lo.y; vf[dt].u[2] = hi.x; vf[dt].u[3] = hi.y;
  }
  const int kb0i = k0 + lg * 4, kb1i = k0 + 16 + lg * 4;
#pragma unroll
  for (int qt = 0; qt < 2; ++qt) {
    f32x4 s0 = {}, s1 = {};
    s0 = mfma16(kf00, qa[qt][0], s0);
    s0 = mfma16(kf01, qa[qt][1], s0);
    s1 = mfma16(kf10, qa[qt][0], s1);
    s1 = mfma16(kf11, qa[qt][1], s1);
    const int qq = qw + qt * 16 + l15;
    U pa;
#pragma unroll
    for (int hw = 0; hw < 2; ++hw) {
      bf16x2 t0, t1;
#pragma unroll
      for (int r = 0; r < 2; ++r) {
        int rr = hw * 2 + r;
        float p0 = fexp2(s0[rr]);
        float p1 = fexp2(s1[rr]);
        if (DIAG) {
          p0 = (kb0i + rr < qq) ? p0 : 0.f;
          p1 = (kb1i + rr < qq) ? p1 : 0.f;
        }
        t0[r] = (bf16)p0;
        t1[r] = (bf16)p1;
      }
      pa.u[hw] = __builtin_bit_cast(unsigned int, t0);
      pa.u[hw + 2] = __builtin_bit_cast(unsigned int, t1);
    }
#pragma unroll
    for (int dt = 0; dt < 4; ++dt)
      acc[qt][dt] = mfma16(pa.v, vf[dt].v, acc[qt][dt]);
  }
}

__global__ __launch_bounds__(256, 2) void attn_ctx(const bf16* __restrict__ Qb,
                                                   const bf16* __restrict__ Kb,
                                                   const bf16* __restrict__ Vt,
                                                   bf16* __restrict__ P0,
                                                   bf16* __restrict__ P1,
                                                   bf16* __restrict__ P2,
                                                   bf16* __restrict__ P3) {
  __shared__ __align__(16) bf16 sK[2 * 32 * 32];  // [kk][k][32 d-half], 4KB
  __shared__ __align__(16) bf16 sV[64 * 32];      // tile-major [d][k], 4KB
  int bh, a, b2;
  swz1024(blockIdx.x, bh, a, b2);
  const int pr = a & 7;                 // pair index 0..7
  const int j = (b2 << 1) | (a >> 3);   // k-split stripe 0..3
  const int tid = threadIdx.x, l = tid & 63, w = tid >> 6;
  const int l15 = l & 15, lg = l >> 4;
  const bf16* Q = Qb + (size_t)bh * SS * HD;
  const bf16* Kh = Kb + (size_t)bh * SS * HD;
  const bf16* V = Vt + (size_t)bh * SS * HD;  // tile-major, rz-prescaled
  bf16* ctxP = (j == 0) ? P0 : (j == 1) ? P1 : (j == 2) ? P2 : P3;
  const int b = bh >> 4, h = bh & 15;

  const int skk = tid >> 7, sr = (tid >> 2) & 31, sc = tid & 3;
  const int scs = sc ^ ((sr >> 1) & 3);          // K source chunk
  const int vr = tid >> 2;                       // V row 0..63
  const int vcs = (tid & 3) ^ ((vr >> 1) & 3);   // V source chunk
  bf16* dK = sK + (size_t)w * 512;  // wave-uniform dest base (64 slots x 8 elems)
  bf16* dV = sV + (size_t)w * 512;

  for (int half = 0; half < 2; ++half) {
    const int T = half ? (15 - pr) : pr;
    const int q0 = T * 128;
    const int qw = q0 + w * 32;  // this wave's 32 q rows

    bf16x8 qa[2][2];
#pragma unroll
    for (int qt = 0; qt < 2; ++qt)
#pragma unroll
      for (int kk = 0; kk < 2; ++kk)
        qa[qt][kk] = *(const bf16x8*)&Q[(qw + qt * 16 + l15) * HD + kk * 32 + lg * 8];

    f32x4 acc[2][4] = {};  // [qt][dt]
    const int kend = q0 + 128;
    for (int k0 = j * 32; k0 < kend; k0 += 128) {
      const bf16* gK = Kh + (size_t)(k0 + sr) * HD + skk * 32 + scs * 8;
      const bf16* gV = V + (((size_t)(k0 >> 5)) << 11) + vr * 32 + vcs * 8;
      __builtin_amdgcn_global_load_lds((const AS1 void*)gK, (AS3 void*)dK, 16, 0, 0);
      __builtin_amdgcn_global_load_lds((const AS1 void*)gV, (AS3 void*)dV, 16, 0, 0);
      __syncthreads();
      if (k0 < qw)
        chunk_compute<false>(sK, sV, k0, qw, qa, acc, l15, lg);
      else if (k0 == qw)
        chunk_compute<true>(sK, sV, k0, qw, qa, acc, l15, lg);
      __syncthreads();
    }

#pragma unroll
    for (int qt = 0; qt < 2; ++qt)
#pragma unroll
      for (int r = 0; r < 4; ++r) {
        int q = qw + qt * 16 + lg * 4 + r;
#pragma unroll
        for (int dt = 0; dt < 4; ++dt)
          ctxP[((size_t)(b * SS + q)) * DD + h * HD + dt * 16 + l15] =
              (bf16)acc[qt][dt][r];
      }
  }
}

// ---------------- combine 4 partial ctx + vlast -> final bf16 ctx (in place on P0) ------
__global__ __launch_bounds__(256) void ctxfin(const bf16* __restrict__ P1,
                                              const bf16* __restrict__ P2,
                                              const bf16* __restrict__ P3,
                                              const float* __restrict__ vlastB,
                                              bf16* __restrict__ ctx) {
  int i = blockIdx.x * 256 + threadIdx.x;  // bf16x8 index over [4096][1024]
  int e0 = i * 8;
  int row = e0 >> 10, col = e0 & (DD - 1);
  int b = row >> 11;
  int vidx = (b * HH + (col >> 6)) * 64 + (col & 63);
  bf16x8 p0 = ((const bf16x8*)ctx)[i];
  bf16x8 p1 = ((const bf16x8*)P1)[i];
  bf16x8 p2 = ((const bf16x8*)P2)[i];
  bf16x8 p3 = ((const bf16x8*)P3)[i];
  f32x4 v0 = *(const f32x4*)&vlastB[vidx];
  f32x4 v1 = *(const f32x4*)&vlastB[vidx + 4];
  bf16x8 o;
#pragma unroll
  for (int jj = 0; jj < 4; ++jj)
    o[jj] = (bf16)(((float)p0[jj] + (float)p1[jj]) + ((float)p2[jj] + (float)p3[jj]) + v0[jj]);
#pragma unroll
  for (int jj = 0; jj < 4; ++jj)
    o[4 + jj] = (bf16)(((float)p0[4 + jj] + (float)p1[4 + jj]) +
                       ((float)p2[4 + jj] + (float)p3[4 + jj]) + v1[jj]);
  ((bf16x8*)ctx)[i] = o;
}

// ---------------- launcher ----------------
extern "C" void kernel_launch(void* const* d_in, const int* in_sizes, int n_in,
                              void* d_out, int out_size, void* d_ws, size_t ws_size,
                              hipStream_t stream) {
  const float* q  = (const float*)d_in[0];
  const float* k  = (const float*)d_in[1];
  const float* v  = (const float*)d_in[2];
  const float* Wq = (const float*)d_in[3];
  const float* bq = (const float*)d_in[4];
  const float* Wk = (const float*)d_in[5];
  const float* bk = (const float*)d_in[6];
  const float* Wv = (const float*)d_in[7];
  const float* bv = (const float*)d_in[8];
  const float* Wo = (const float*)d_in[9];
  const float* bo = (const float*)d_in[10];

  char* ws = (char*)d_ws;
  const size_t SZP = (size_t)4096 * 1024 * 2;  // 8 MiB
  const size_t SZW = (size_t)1024 * 1024 * 2;  // 2 MiB
  bf16* Qb   = (bf16*)(ws + 0 * SZP);          // [BH][S][64] (prescaled)
  bf16* Kb   = (bf16*)(ws + 1 * SZP);          // [BH][S][64]
  bf16* Vt   = (bf16*)(ws + 2 * SZP);          // [BH][64][64][32] tile-major (rz-prescaled)
  bf16* ctxb = (bf16*)(ws + 3 * SZP);          // ctx partial 0 -> final ctx
  bf16* P1   = (bf16*)(ws + 4 * SZP);          // ctx partial 1
  bf16* P2   = (bf16*)(ws + 5 * SZP);          // ctx partial 2
  bf16* P3   = (bf16*)(ws + 6 * SZP);          // ctx partial 3
  bf16* Wqb  = (bf16*)(ws + 7 * SZP + 0 * SZW);
  bf16* Wkb  = (bf16*)(ws + 7 * SZP + 1 * SZW);
  bf16* Wvb  = (bf16*)(ws + 7 * SZP + 2 * SZW);
  bf16* Wob  = (bf16*)(ws + 7 * SZP + 3 * SZW);
  float* zPart = (float*)(ws + 7 * SZP + 4 * SZW);     // [2][BH][SS] fp32
  float* vlastB = zPart + (size_t)2 * BH * SS;         // [BH][64] fp32

  cvt_w<<<dim3(512, 4), 256, 0, stream>>>(Wq, Wk, Wv, Wo, Wqb, Wkb, Wvb, Wob);

  proj_gemm<<<768, 256, 0, stream>>>(
      q, k, v, Wqb, Wkb, Wvb, bq, bk, bv, Qb, Kb, Vt);

  colz<<<1024, 256, 0, stream>>>(Qb, Kb, zPart);
  vscale<<<(BH * HD * SS / 8) / 256, 256, 0, stream>>>(Vt, zPart, vlastB);
  attn_ctx<<<1024, 256, 0, stream>>>(Qb, Kb, Vt, ctxb, P1, P2, P3);
  ctxfin<<<(4096 * 1024 / 8) / 256, 256, 0, stream>>>(P1, P2, P3, vlastB, ctxb);

  out_gemm<<<256, 256, 0, stream>>>(ctxb, Wob, bo, (float*)d_out);
}

// Round 21
// 141.439 us; speedup vs baseline: 1.0191x; 1.0191x over previous
//
#include <hip/hip_runtime.h>

typedef __bf16 bf16;
typedef __attribute__((ext_vector_type(8))) __bf16 bf16x8;
typedef __attribute__((ext_vector_type(2))) __bf16 bf16x2;
typedef __attribute__((ext_vector_type(4))) float f32x4;

#define AS1 __attribute__((address_space(1)))
#define AS3 __attribute__((address_space(3)))

// Problem constants
#define BB 2
#define SS 2048
#define DD 1024
#define HH 16
#define HD 64
#define BH (BB*HH)

// 0.125 (1/sqrt(64)) * 1/ln(2): folded into Q so scores come out in log2 units
#define QSCALE 0.1803368801111244f

static __device__ __forceinline__ f32x4 mfma16(bf16x8 a, bf16x8 b, f32x4 c) {
  return __builtin_amdgcn_mfma_f32_16x16x32_bf16(a, b, c, 0, 0, 0);
}
static __device__ __forceinline__ float fexp2(float x) {
  return __builtin_amdgcn_exp2f(x);
}

// XCD-aware remap, 1024-block grids: all 32 blocks of a bh on one XCD.
static __device__ __forceinline__ void swz1024(int bid, int& bh, int& a, int& b2) {
  int c = bid & 7, j = bid >> 3;
  bh = c + 8 * (j & 3);
  int rem = j >> 2;          // 0..31
  a = rem & 15;
  b2 = rem >> 4;
}

// ---------------- fp32 -> bf16 conversion (weights only; inputs fused into proj) --------
__global__ __launch_bounds__(256) void cvt_w(const float* __restrict__ s0, const float* __restrict__ s1,
                                             const float* __restrict__ s2, const float* __restrict__ s3,
                                             bf16* __restrict__ o0, bf16* __restrict__ o1,
                                             bf16* __restrict__ o2, bf16* __restrict__ o3) {
  const int z = blockIdx.y;
  const float* s = (z == 0) ? s0 : (z == 1) ? s1 : (z == 2) ? s2 : s3;
  bf16* o = (z == 0) ? o0 : (z == 1) ? o1 : (z == 2) ? o2 : o3;
  int i = blockIdx.x * 256 + threadIdx.x;
  const float4* sp = (const float4*)s;
  float4 a = sp[2 * i], b = sp[2 * i + 1];
  bf16x8 v;
  v[0] = (bf16)a.x; v[1] = (bf16)a.y; v[2] = (bf16)a.z; v[3] = (bf16)a.w;
  v[4] = (bf16)b.x; v[5] = (bf16)b.y; v[6] = (bf16)b.z; v[7] = (bf16)b.w;
  ((bf16x8*)o)[i] = v;
}

// ---------------- batched QKV projection, cvt_x FUSED via fp32 LDS staging --------------
// 1D grid 768, XCD decode: XCD c owns m-tiles [4c,4c+4) across all n,z.
// A staged RAW fp32 via global_load_lds (async path preserved); converted to bf16 at
// fragment-read. A rows are 128B (wrap all 32 banks) -> row swizzle slot' = slot^(row&7),
// inverse-permuted global source (rule #21). B: bf16, old ((row>>1)&3) swizzle.
// z=0: Q (prescaled) -> [BH][S][64]; z=1: K -> [BH][S][64]; z=2: V tile-major.
__global__ __launch_bounds__(256) void proj_gemm(
    const float* __restrict__ Xq, const float* __restrict__ Xk, const float* __restrict__ Xv,
    const bf16* __restrict__ Wq, const bf16* __restrict__ Wk, const bf16* __restrict__ Wv,
    const float* __restrict__ bq, const float* __restrict__ bk, const float* __restrict__ bv,
    bf16* __restrict__ Oq, bf16* __restrict__ Ok, bf16* __restrict__ Ovt) {
  __shared__ __align__(16) float sA[128 * 32];   // fp32 A tile, 16 KB
  __shared__ __align__(16) bf16 sB[128 * 32];    // bf16 B tile, 8 KB
  const int bid = blockIdx.x;
  const int c = bid & 7, u = bid >> 3;
  const int mt = c * 4 + (u & 3);   // 0..31
  const int nt = (u >> 2) & 7;     // 0..7
  const int z = u >> 5;            // 0..2
  const float* X = (z == 0) ? Xq : ((z == 1) ? Xk : Xv);
  const bf16* W = (z == 0) ? Wq : ((z == 1) ? Wk : Wv);
  const float* bias = (z == 0) ? bq : ((z == 1) ? bk : bv);
  const int tid = threadIdx.x, l = tid & 63, w = tid >> 6;
  const int m0 = mt * 128, n0 = nt * 128;
  const int l15 = l & 15, lg = l >> 4;
  const int wr = (w >> 1) * 64, wc = (w & 1) * 64;
  const int fB = (l15 >> 1) & 3;  // B row-swizzle factor
  const int fA = l15 & 7;         // A row-swizzle factor (wr, m*16 ≡ 0 mod 8)
  f32x4 acc[4][4] = {};
  for (int kt = 0; kt < DD; kt += 32) {
    // stage A: 1024 16B-slots (4 fp32 each); slot s of row r <- global chunk (s&7)^(r&7)
#pragma unroll
    for (int i = 0; i < 4; ++i) {
      int s = i * 256 + tid;
      int r = s >> 3, cs = (s & 7) ^ (r & 7);
      const float* ga = X + (size_t)(m0 + r) * DD + kt + cs * 4;
      __builtin_amdgcn_global_load_lds((const AS1 void*)ga, (AS3 void*)(sA + s * 4), 16, 0, 0);
    }
    // stage B: 512 16B-slots (8 bf16 each); chunk (t&3)^((r>>1)&3)
#pragma unroll
    for (int i = 0; i < 2; ++i) {
      int t = i * 256 + tid;
      int r = t >> 2, cs = (t & 3) ^ ((r >> 1) & 3);
      const bf16* gb = W + (size_t)(n0 + r) * DD + kt + cs * 8;
      __builtin_amdgcn_global_load_lds((const AS1 void*)gb, (AS3 void*)(sB + t * 8), 16, 0, 0);
    }
    __syncthreads();
    bf16x8 af[4], bfr[4];
#pragma unroll
    for (int m = 0; m < 4; ++m) {
      const float* base = sA + (wr + m * 16 + l15) * 32;
      f32x4 u0 = *(const f32x4*)(base + (((2 * lg) ^ fA) << 2));
      f32x4 u1 = *(const f32x4*)(base + (((2 * lg + 1) ^ fA) << 2));
      bf16x8 o;
      o[0] = (bf16)u0[0]; o[1] = (bf16)u0[1]; o[2] = (bf16)u0[2]; o[3] = (bf16)u0[3];
      o[4] = (bf16)u1[0]; o[5] = (bf16)u1[1]; o[6] = (bf16)u1[2]; o[7] = (bf16)u1[3];
      af[m] = o;
    }
#pragma unroll
    for (int n = 0; n < 4; ++n)
      bfr[n] = *(const bf16x8*)(sB + (wc + n * 16 + l15) * 32 + (lg ^ fB) * 8);
#pragma unroll
    for (int m = 0; m < 4; ++m)
#pragma unroll
      for (int n = 0; n < 4; ++n)
        acc[m][n] = mfma16(af[m], bfr[n], acc[m][n]);
    __syncthreads();
  }
#pragma unroll
  for (int n = 0; n < 4; ++n) {
    int col = n0 + wc + n * 16 + l15;
    float bb = bias[col];
    int h = col >> 6, d = col & 63;
#pragma unroll
    for (int m = 0; m < 4; ++m) {
#pragma unroll
      for (int r = 0; r < 4; ++r) {
        int row = m0 + wr + m * 16 + lg * 4 + r;
        int b = row >> 11, s = row & (SS - 1);
        float vv = acc[m][n][r] + bb;
        if (z == 0) vv *= QSCALE;
        if (z != 2)
          ((z == 0) ? Oq : Ok)[(((size_t)(b * HH + h)) * SS + s) * HD + d] = (bf16)vv;
        else
          Ovt[(size_t)(b * HH + h) * SS * HD + ((s >> 5) * 64 + d) * 32 + (s & 31)] = (bf16)vv;
      }
    }
  }
}

// ---------------- core 128x128 bf16 NT GEMM (C = A * B^T), BK=32 (out_gemm) -------------
__device__ __forceinline__ void gemm_core(const bf16* __restrict__ A,
                                          const bf16* __restrict__ Bm, int K,
                                          int m0, int n0, int w, int l,
                                          bf16* sA, bf16* sB, f32x4 (&acc)[4][4]) {
  const int l15 = l & 15, lg = l >> 4;
  const int wr = (w >> 1) * 64, wc = (w & 1) * 64;
  const int fv = (l15 >> 1) & 3;
  for (int kt = 0; kt < K; kt += 32) {
#pragma unroll
    for (int i = 0; i < 2; ++i) {
      int t = i * 256 + w * 64 + l;
      const int r = t >> 2, cs = (t & 3) ^ ((r >> 1) & 3);
      const bf16* ga = A + (size_t)(m0 + r) * K + kt + cs * 8;
      const bf16* gb = Bm + (size_t)(n0 + r) * K + kt + cs * 8;
      __builtin_amdgcn_global_load_lds((const AS1 void*)ga,
                                       (AS3 void*)(sA + (i * 256 + w * 64) * 8), 16, 0, 0);
      __builtin_amdgcn_global_load_lds((const AS1 void*)gb,
                                       (AS3 void*)(sB + (i * 256 + w * 64) * 8), 16, 0, 0);
    }
    __syncthreads();
    bf16x8 af[4], bfr[4];
#pragma unroll
    for (int m = 0; m < 4; ++m)
      af[m] = *(const bf16x8*)(sA + (wr + m * 16 + l15) * 32 + (lg ^ fv) * 8);
#pragma unroll
    for (int n = 0; n < 4; ++n)
      bfr[n] = *(const bf16x8*)(sB + (wc + n * 16 + l15) * 32 + (lg ^ fv) * 8);
#pragma unroll
    for (int m = 0; m < 4; ++m)
#pragma unroll
      for (int n = 0; n < 4; ++n)
        acc[m][n] = mfma16(af[m], bfr[n], acc[m][n]);
    __syncthreads();
  }
}

// ---------------- output projection: out = ctx @ Wo^T + bo (fp32 out) ----------------
__global__ __launch_bounds__(256) void out_gemm(const bf16* __restrict__ A,
                                                const bf16* __restrict__ W,
                                                const float* __restrict__ bias,
                                                float* __restrict__ out) {
  __shared__ __align__(16) bf16 sA[128 * 32];
  __shared__ __align__(16) bf16 sB[128 * 32];
  const int bid = blockIdx.x;
  const int c = bid & 7, u = bid >> 3;
  const int mt = c * 4 + (u & 3);   // 0..31
  const int nt = (u >> 2) & 7;     // 0..7
  const int tid = threadIdx.x, l = tid & 63, w = tid >> 6;
  const int m0 = mt * 128, n0 = nt * 128;
  f32x4 acc[4][4] = {};
  gemm_core(A, W, DD, m0, n0, w, l, sA, sB, acc);
  const int l15 = l & 15, lg = l >> 4;
  const int wr = (w >> 1) * 64, wc = (w & 1) * 64;
#pragma unroll
  for (int n = 0; n < 4; ++n) {
    int col = n0 + wc + n * 16 + l15;
    float bb = bias[col];
#pragma unroll
    for (int m = 0; m < 4; ++m)
#pragma unroll
      for (int r = 0; r < 4; ++r) {
        int row = m0 + wr + m * 16 + lg * 4 + r;
        out[(size_t)row * DD + col] = acc[m][n][r] + bb;
      }
  }
}

// ---------------- pass A: per-column partial softmax denominator -----------------------
__global__ __launch_bounds__(256) void colz(const bf16* __restrict__ Qb,
                                            const bf16* __restrict__ Kb,
                                            float* __restrict__ zPart) {
  __shared__ float zred[4][64];
  int bh, pair, qh;
  swz1024(blockIdx.x, bh, pair, qh);
  const int tid = threadIdx.x, l = tid & 63, w = tid >> 6;
  const int l15 = l & 15, lg = l >> 4;
  const bf16* Q = Qb + (size_t)bh * SS * HD;
  const bf16* Kh = Kb + (size_t)bh * SS * HD;

  for (int half = 0; half < 2; ++half) {
    const int s = half ? (31 - pair) : pair;
    const int c0 = s * 64;
    bf16x8 kf[4][2];
#pragma unroll
    for (int kt = 0; kt < 4; ++kt) {
      kf[kt][0] = *(const bf16x8*)&Kh[(c0 + kt * 16 + l15) * HD + lg * 8];
      kf[kt][1] = *(const bf16x8*)&Kh[(c0 + kt * 16 + l15) * HD + 32 + lg * 8];
    }
    float z[4] = {};
    const int qstart = c0 + qh * 64 + w * 16;
    bf16x8 qa0, qa1, qn0, qn1;
    if (qstart < SS) {
      qa0 = *(const bf16x8*)&Q[(qstart + l15) * HD + lg * 8];
      qa1 = *(const bf16x8*)&Q[(qstart + l15) * HD + 32 + lg * 8];
    }
    for (int qb = qstart; qb < SS; qb += 128) {
      const int qnext = qb + 128;
      if (qnext < SS) {
        qn0 = *(const bf16x8*)&Q[(qnext + l15) * HD + lg * 8];
        qn1 = *(const bf16x8*)&Q[(qnext + l15) * HD + 32 + lg * 8];
      }
      f32x4 d[4] = {};
#pragma unroll
      for (int kt = 0; kt < 4; ++kt) {
        d[kt] = mfma16(qa0, kf[kt][0], d[kt]);
        d[kt] = mfma16(qa1, kf[kt][1], d[kt]);
      }
#pragma unroll
      for (int kt = 0; kt < 4; ++kt) {
        const int kcol = c0 + kt * 16 + l15;
#pragma unroll
        for (int r = 0; r < 4; ++r) {
          int qq = qb + lg * 4 + r;
          z[kt] += (qq > kcol) ? fexp2(d[kt][r]) : 0.f;
        }
      }
      qa0 = qn0; qa1 = qn1;
    }
#pragma unroll
    for (int kt = 0; kt < 4; ++kt) {
      z[kt] += __shfl_xor(z[kt], 16);
      z[kt] += __shfl_xor(z[kt], 32);
    }
    if (l < 16) {
#pragma unroll
      for (int kt = 0; kt < 4; ++kt) zred[w][kt * 16 + l15] = z[kt];
    }
    __syncthreads();
    if (tid < 64) {
      float zs = zred[0][tid] + zred[1][tid] + zred[2][tid] + zred[3][tid];
      zPart[((size_t)qh * BH + bh) * SS + c0 + tid] = zs;
    }
    __syncthreads();
  }
}

// ---------------- prescale tile-major V by rz = 1/(z0+z1) (rzfin fused); save vlast -----
__global__ __launch_bounds__(256) void vscale(bf16* __restrict__ Vt,
                                              const float* __restrict__ zPart,
                                              float* __restrict__ vlastB) {
  int i = blockIdx.x * 256 + threadIdx.x;  // bf16x8 index over BH*64*64*4
  int ks8 = i & 3;
  int d = (i >> 2) & 63;
  int ts = (i >> 8) & 63;
  int bh = i >> 14;
  bf16* p = Vt + ((((size_t)bh * 64 + ts) * 64 + d) * 32) + ks8 * 8;
  const float* z0 = zPart + (size_t)bh * SS + ts * 32 + ks8 * 8;
  const float* z1 = zPart + ((size_t)BH + bh) * SS + ts * 32 + ks8 * 8;
  bf16x8 v = *(const bf16x8*)p;
  if (ts == 63 && ks8 == 3) vlastB[bh * 64 + d] = (float)v[7] * (1.0f / (float)SS);
  f32x4 a0 = *(const f32x4*)z0, a1 = *(const f32x4*)(z0 + 4);
  f32x4 b0 = *(const f32x4*)z1, b1 = *(const f32x4*)(z1 + 4);
  f32x4 r0, r1;
#pragma unroll
  for (int j = 0; j < 4; ++j) {
    float s0 = a0[j] + b0[j], s1 = a1[j] + b1[j];
    r0[j] = (s0 > 0.f) ? 1.0f / s0 : 0.f;
    r1[j] = (s1 > 0.f) ? 1.0f / s1 : 0.f;
  }
  bf16x8 o;
#pragma unroll
  for (int j = 0; j < 4; ++j) o[j] = (bf16)((float)v[j] * r0[j]);
#pragma unroll
  for (int j = 0; j < 4; ++j) o[4 + j] = (bf16)((float)v[4 + j] * r1[j]);
  *(bf16x8*)p = o;
}

// ---------------- pass B: LDS-staged flash loop with XOR-swizzled tiles -----------------
template <bool DIAG>
static __device__ __forceinline__ void chunk_compute(
    const bf16* sKe, const bf16* sVe, int k0, int qw,
    const bf16x8 (&qa)[2][2], f32x4 (&acc)[2][4], int l15, int lg) {
  const int fv = (l15 >> 1) & 3;           // row-swizzle factor (row mod 16 ≡ l15)
  const int slK = (lg ^ fv) * 8;
  bf16x8 kf00 = *(const bf16x8*)(sKe + l15 * 32 + slK);
  bf16x8 kf01 = *(const bf16x8*)(sKe + 1024 + l15 * 32 + slK);
  bf16x8 kf10 = *(const bf16x8*)(sKe + (16 + l15) * 32 + slK);
  bf16x8 kf11 = *(const bf16x8*)(sKe + 1024 + (16 + l15) * 32 + slK);
  union U { unsigned int u[4]; bf16x8 v; };
  U vf[4];
#pragma unroll
  for (int dt = 0; dt < 4; ++dt) {
    const bf16* base = sVe + (dt * 16 + l15) * 32;
    uint2 lo = *(const uint2*)&base[((lg >> 1) ^ fv) * 8 + (lg & 1) * 4];
    uint2 hi = *(const uint2*)&base[(((lg >> 1) + 2) ^ fv) * 8 + (lg & 1) * 4];
    vf[dt].u[0] = lo.x; vf[dt].u[1] = lo.y; vf[dt].u[2] = hi.x; vf[dt].u[3] = hi.y;
  }
  const int kb0i = k0 + lg * 4, kb1i = k0 + 16 + lg * 4;
#pragma unroll
  for (int qt = 0; qt < 2; ++qt) {
    f32x4 s0 = {}, s1 = {};
    s0 = mfma16(kf00, qa[qt][0], s0);
    s0 = mfma16(kf01, qa[qt][1], s0);
    s1 = mfma16(kf10, qa[qt][0], s1);
    s1 = mfma16(kf11, qa[qt][1], s1);
    const int qq = qw + qt * 16 + l15;
    U pa;
#pragma unroll
    for (int hw = 0; hw < 2; ++hw) {
      bf16x2 t0, t1;
#pragma unroll
      for (int r = 0; r < 2; ++r) {
        int rr = hw * 2 + r;
        float p0 = fexp2(s0[rr]);
        float p1 = fexp2(s1[rr]);
        if (DIAG) {
          p0 = (kb0i + rr < qq) ? p0 : 0.f;
          p1 = (kb1i + rr < qq) ? p1 : 0.f;
        }
        t0[r] = (bf16)p0;
        t1[r] = (bf16)p1;
      }
      pa.u[hw] = __builtin_bit_cast(unsigned int, t0);
      pa.u[hw + 2] = __builtin_bit_cast(unsigned int, t1);
    }
#pragma unroll
    for (int dt = 0; dt < 4; ++dt)
      acc[qt][dt] = mfma16(pa.v, vf[dt].v, acc[qt][dt]);
  }
}

__global__ __launch_bounds__(256, 2) void attn_ctx(const bf16* __restrict__ Qb,
                                                   const bf16* __restrict__ Kb,
                                                   const bf16* __restrict__ Vt,
                                                   bf16* __restrict__ P0,
                                                   bf16* __restrict__ P1,
                                                   bf16* __restrict__ P2,
                                                   bf16* __restrict__ P3) {
  __shared__ __align__(16) bf16 sK[2 * 32 * 32];  // [kk][k][32 d-half], 4KB
  __shared__ __align__(16) bf16 sV[64 * 32];      // tile-major [d][k], 4KB
  int bh, a, b2;
  swz1024(blockIdx.x, bh, a, b2);
  const int pr = a & 7;                 // pair index 0..7
  const int j = (b2 << 1) | (a >> 3);   // k-split stripe 0..3
  const int tid = threadIdx.x, l = tid & 63, w = tid >> 6;
  const int l15 = l & 15, lg = l >> 4;
  const bf16* Q = Qb + (size_t)bh * SS * HD;
  const bf16* Kh = Kb + (size_t)bh * SS * HD;
  const bf16* V = Vt + (size_t)bh * SS * HD;  // tile-major, rz-prescaled
  bf16* ctxP = (j == 0) ? P0 : (j == 1) ? P1 : (j == 2) ? P2 : P3;
  const int b = bh >> 4, h = bh & 15;

  // staging decomposition: LDS dest linear (byte = tid*16); global source chunk index
  // inverse-swizzled so LDS slot s of row r holds global chunk s ^ ((r>>1)&3).
  const int skk = tid >> 7, sr = (tid >> 2) & 31, sc = tid & 3;
  const int scs = sc ^ ((sr >> 1) & 3);          // K source chunk
  const int vr = tid >> 2;                       // V row 0..63
  const int vcs = (tid & 3) ^ ((vr >> 1) & 3);   // V source chunk
  bf16* dK = sK + (size_t)w * 512;  // wave-uniform dest base (64 slots x 8 elems)
  bf16* dV = sV + (size_t)w * 512;

  for (int half = 0; half < 2; ++half) {
    const int T = half ? (15 - pr) : pr;
    const int q0 = T * 128;
    const int qw = q0 + w * 32;  // this wave's 32 q rows

    bf16x8 qa[2][2];
#pragma unroll
    for (int qt = 0; qt < 2; ++qt)
#pragma unroll
      for (int kk = 0; kk < 2; ++kk)
        qa[qt][kk] = *(const bf16x8*)&Q[(qw + qt * 16 + l15) * HD + kk * 32 + lg * 8];

    f32x4 acc[2][4] = {};  // [qt][dt]
    const int kend = q0 + 128;
    for (int k0 = j * 32; k0 < kend; k0 += 128) {
      // stage K (re-tiled [kk][k][32]) and V (tile-major) with pre-swizzled sources
      const bf16* gK = Kh + (size_t)(k0 + sr) * HD + skk * 32 + scs * 8;
      const bf16* gV = V + (((size_t)(k0 >> 5)) << 11) + vr * 32 + vcs * 8;
      __builtin_amdgcn_global_load_lds((const AS1 void*)gK, (AS3 void*)dK, 16, 0, 0);
      __builtin_amdgcn_global_load_lds((const AS1 void*)gV, (AS3 void*)dV, 16, 0, 0);
      __syncthreads();
      if (k0 < qw)
        chunk_compute<false>(sK, sV, k0, qw, qa, acc, l15, lg);
      else if (k0 == qw)
        chunk_compute<true>(sK, sV, k0, qw, qa, acc, l15, lg);
      __syncthreads();
    }

    // write this wave's rows of the j-th partial ctx
#pragma unroll
    for (int qt = 0; qt < 2; ++qt)
#pragma unroll
      for (int r = 0; r < 4; ++r) {
        int q = qw + qt * 16 + lg * 4 + r;
#pragma unroll
        for (int dt = 0; dt < 4; ++dt)
          ctxP[((size_t)(b * SS + q)) * DD + h * HD + dt * 16 + l15] =
              (bf16)acc[qt][dt][r];
      }
  }
}

// ---------------- combine 4 partial ctx + vlast -> final bf16 ctx (in place on P0) ------
__global__ __launch_bounds__(256) void ctxfin(const bf16* __restrict__ P1,
                                              const bf16* __restrict__ P2,
                                              const bf16* __restrict__ P3,
                                              const float* __restrict__ vlastB,
                                              bf16* __restrict__ ctx) {
  int i = blockIdx.x * 256 + threadIdx.x;  // bf16x8 index over [4096][1024]
  int e0 = i * 8;
  int row = e0 >> 10, col = e0 & (DD - 1);
  int b = row >> 11;
  int vidx = (b * HH + (col >> 6)) * 64 + (col & 63);
  bf16x8 p0 = ((const bf16x8*)ctx)[i];
  bf16x8 p1 = ((const bf16x8*)P1)[i];
  bf16x8 p2 = ((const bf16x8*)P2)[i];
  bf16x8 p3 = ((const bf16x8*)P3)[i];
  f32x4 v0 = *(const f32x4*)&vlastB[vidx];
  f32x4 v1 = *(const f32x4*)&vlastB[vidx + 4];
  bf16x8 o;
#pragma unroll
  for (int jj = 0; jj < 4; ++jj)
    o[jj] = (bf16)(((float)p0[jj] + (float)p1[jj]) + ((float)p2[jj] + (float)p3[jj]) + v0[jj]);
#pragma unroll
  for (int jj = 0; jj < 4; ++jj)
    o[4 + jj] = (bf16)(((float)p0[4 + jj] + (float)p1[4 + jj]) +
                       ((float)p2[4 + jj] + (float)p3[4 + jj]) + v1[jj]);
  ((bf16x8*)ctx)[i] = o;
}

// ---------------- launcher ----------------
extern "C" void kernel_launch(void* const* d_in, const int* in_sizes, int n_in,
                              void* d_out, int out_size, void* d_ws, size_t ws_size,
                              hipStream_t stream) {
  const float* q  = (const float*)d_in[0];
  const float* k  = (const float*)d_in[1];
  const float* v  = (const float*)d_in[2];
  const float* Wq = (const float*)d_in[3];
  const float* bq = (const float*)d_in[4];
  const float* Wk = (const float*)d_in[5];
  const float* bk = (const float*)d_in[6];
  const float* Wv = (const float*)d_in[7];
  const float* bv = (const float*)d_in[8];
  const float* Wo = (const float*)d_in[9];
  const float* bo = (const float*)d_in[10];

  char* ws = (char*)d_ws;
  const size_t SZP = (size_t)4096 * 1024 * 2;  // 8 MiB
  const size_t SZW = (size_t)1024 * 1024 * 2;  // 2 MiB
  bf16* Qb   = (bf16*)(ws + 0 * SZP);          // [BH][S][64] (prescaled)
  bf16* Kb   = (bf16*)(ws + 1 * SZP);          // [BH][S][64]
  bf16* Vt   = (bf16*)(ws + 2 * SZP);          // [BH][64][64][32] tile-major (rz-prescaled)
  bf16* ctxb = (bf16*)(ws + 3 * SZP);          // ctx partial 0 -> final ctx
  bf16* P1   = (bf16*)(ws + 4 * SZP);          // ctx partial 1
  bf16* P2   = (bf16*)(ws + 5 * SZP);          // ctx partial 2
  bf16* P3   = (bf16*)(ws + 6 * SZP);          // ctx partial 3
  bf16* Wqb  = (bf16*)(ws + 7 * SZP + 0 * SZW);
  bf16* Wkb  = (bf16*)(ws + 7 * SZP + 1 * SZW);
  bf16* Wvb  = (bf16*)(ws + 7 * SZP + 2 * SZW);
  bf16* Wob  = (bf16*)(ws + 7 * SZP + 3 * SZW);
  float* zPart = (float*)(ws + 7 * SZP + 4 * SZW);     // [2][BH][SS] fp32
  float* vlastB = zPart + (size_t)2 * BH * SS;         // [BH][64] fp32

  cvt_w<<<dim3(512, 4), 256, 0, stream>>>(Wq, Wk, Wv, Wo, Wqb, Wkb, Wvb, Wob);

  proj_gemm<<<768, 256, 0, stream>>>(
      q, k, v, Wqb, Wkb, Wvb, bq, bk, bv, Qb, Kb, Vt);

  colz<<<1024, 256, 0, stream>>>(Qb, Kb, zPart);
  vscale<<<(BH * HD * SS / 8) / 256, 256, 0, stream>>>(Vt, zPart, vlastB);
  attn_ctx<<<1024, 256, 0, stream>>>(Qb, Kb, Vt, ctxb, P1, P2, P3);
  ctxfin<<<(4096 * 1024 / 8) / 256, 256, 0, stream>>>(P1, P2, P3, vlastB, ctxb);

  out_gemm<<<256, 256, 0, stream>>>(ctxb, Wob, bo, (float*)d_out);
}